// Round 2
// baseline (4319.912 us; speedup 1.0000x reference)
//
#include <hip/hip_runtime.h>
#include <hip/hip_bf16.h>
#include <stdint.h>

typedef unsigned short u16;
typedef short short8 __attribute__((ext_vector_type(8)));
typedef float floatx4 __attribute__((ext_vector_type(4)));
typedef float f32x4 __attribute__((ext_vector_type(4)));

// ---------- numerics helpers ----------
__device__ __forceinline__ u16 f2bf(float f) {
  union { float f; uint32_t u; } v; v.f = f;
  return (u16)((v.u + 0x7FFFu + ((v.u >> 16) & 1u)) >> 16);
}
__device__ __forceinline__ float fexp(float x) {
  return __builtin_amdgcn_exp2f(x * 1.44269504088896340736f);
}
__device__ __forceinline__ float sigm(float x) {
  return __builtin_amdgcn_rcpf(1.0f + fexp(-x));
}
__device__ __forceinline__ float tanh_(float x) {
  return 1.0f - 2.0f * __builtin_amdgcn_rcpf(1.0f + fexp(2.0f * x));
}
// pack two f32 -> (bf16(hi)<<16)|bf16(lo), round-half-up via +0x8000 then byte-perm
__device__ __forceinline__ uint32_t packbf(float hi, float lo) {
  union { float f; uint32_t u; } a, b; a.f = hi; b.f = lo;
  return __builtin_amdgcn_perm(a.u + 0x8000u, b.u + 0x8000u, 0x07060302u);
}

// ---------- K1: weight transpose + bf16 convert ----------
// Wi,Wh: [256][1024] fp32 (k-major). Wi_t/Wh_t: [1024][256] bf16 so MFMA
// B-fragments (8 consecutive k per lane) are contiguous 16B loads.
__global__ void k1_prep(const float* __restrict__ Wi, const float* __restrict__ Wh,
                        u16* __restrict__ Wi_t, u16* __restrict__ Wh_t) {
  const int idx = blockIdx.x * 256 + threadIdx.x;   // 0..262143
  const int n = idx >> 8, k = idx & 255;
  Wi_t[idx] = f2bf(Wi[k * 1024 + n]);
  Wh_t[idx] = f2bf(Wh[k * 1024 + n]);
}

// ---------- K3: fused scan ----------
// 128 blocks x 64 threads. block = (g = blockIdx&7: 16 batch rows,
// j = blockIdx>>3: 16 h-cols -> 4 gate cols sets). Wi and Wh slices register-
// resident (256 VGPRs). Per step: poll flag -> acquire fence (buffer_inv) ->
// h A-frag b128 loads -> 32 h-MFMA -> gates -> publish h (stores + RELEASE
// atomic flag add: vmcnt drain + buffer_wbl2 by compiler) -> y store ->
// x(t+1)@Wi (loads issued early; convert + 32 MFMA in the wait shadow).
// h ring R=4 (proof: flag(t)==16 => all peers consumed h(t-1); we overwrite
// slot of h(t-3)). Correct for ANY block->XCD placement: all cross-block data
// flows through agent-scope release/acquire (MALL-coherent).
__global__ __launch_bounds__(64, 1) void k3_lstm(
    const u16* __restrict__ Wi_t, const u16* __restrict__ Wh_t,
    const float* __restrict__ x, const float* __restrict__ bh,
    u16* __restrict__ h_ring, unsigned int* __restrict__ flags,
    float* __restrict__ out) {
  const int g = blockIdx.x & 7;
  const int j = blockIdx.x >> 3;          // 0..15
  const int l = threadIdx.x;
  const int lq = l >> 4, ln = l & 15;
  const int colBase = j * 16 + ln;        // h-column 0..255

  // register-resident weight B-fragments: [gate][k-chunk]
  short8 bfI[4][8], bfW[4][8];
#pragma unroll
  for (int gp = 0; gp < 4; ++gp)
#pragma unroll
    for (int kk = 0; kk < 8; ++kk) {
      const size_t o = (size_t)(gp * 256 + colBase) * 256 + kk * 32 + lq * 8;
      bfI[gp][kk] = *(const short8*)(Wi_t + o);
      bfW[gp][kk] = *(const short8*)(Wh_t + o);
    }
  float bias[4];
#pragma unroll
  for (int gp = 0; gp < 4; ++gp) bias[gp] = bh[gp * 256 + colBase];

  // xga = xg(t) accumulator (bias + x_t @ Wi slice), in MFMA C layout
  floatx4 xga[4];
  {
    f32x4 xf[16];
    const float* xp = x + (size_t)(g * 16 + ln) * 262144 + lq * 8;  // t=0
#pragma unroll
    for (int kk = 0; kk < 8; ++kk) {
      xf[2 * kk]     = *(const f32x4*)(xp + kk * 32);
      xf[2 * kk + 1] = *(const f32x4*)(xp + kk * 32 + 4);
    }
#pragma unroll
    for (int gp = 0; gp < 4; ++gp)
      xga[gp] = (floatx4){bias[gp], bias[gp], bias[gp], bias[gp]};
#pragma unroll
    for (int kk = 0; kk < 8; ++kk) {
      union { uint32_t u[4]; short8 s; } cv;
      cv.u[0] = packbf(xf[2 * kk][1], xf[2 * kk][0]);
      cv.u[1] = packbf(xf[2 * kk][3], xf[2 * kk][2]);
      cv.u[2] = packbf(xf[2 * kk + 1][1], xf[2 * kk + 1][0]);
      cv.u[3] = packbf(xf[2 * kk + 1][3], xf[2 * kk + 1][2]);
#pragma unroll
      for (int gp = 0; gp < 4; ++gp)
        xga[gp] = __builtin_amdgcn_mfma_f32_16x16x32_bf16(cv.s, bfI[gp][kk],
                                                          xga[gp], 0, 0, 0);
    }
  }

  float creg[4] = {0.f, 0.f, 0.f, 0.f};
  float hv[4]   = {0.f, 0.f, 0.f, 0.f};
  unsigned int* const myflags = flags + g * 1025;

  for (int t = 0; t < 1024; ++t) {
    if (t > 0) {
      unsigned int* fp = myflags + t;
      int spins = 0;
      while (__hip_atomic_load(fp, __ATOMIC_RELAXED, __HIP_MEMORY_SCOPE_AGENT) < 16u &&
             ++spins < 4096) {}
      __builtin_amdgcn_fence(__ATOMIC_ACQUIRE, "agent");  // buffer_inv: no stale L1/L2
    }
    // h(t) A-fragments from ring slot t&3 (issue first)
    const u16* hs = h_ring + (size_t)(t & 3) * 32768 + g * 4096;
    short8 af[8];
#pragma unroll
    for (int kk = 0; kk < 8; ++kk)
      af[kk] = *(const short8*)(hs + ln * 256 + kk * 32 + lq * 8);
    // x(t+1) fp32 loads issued now, consumed after publish (latency hidden)
    f32x4 xf[16];
    if (t < 1023) {
      const float* xp = x + (size_t)(g * 16 + ln) * 262144 + (size_t)(t + 1) * 256 + lq * 8;
#pragma unroll
      for (int kk = 0; kk < 8; ++kk) {
        xf[2 * kk]     = *(const f32x4*)(xp + kk * 32);
        xf[2 * kk + 1] = *(const f32x4*)(xp + kk * 32 + 4);
      }
    }
    // gates = xga + h(t) @ Wh slice
    floatx4 acc[4];
#pragma unroll
    for (int gp = 0; gp < 4; ++gp) acc[gp] = xga[gp];
#pragma unroll
    for (int kk = 0; kk < 8; ++kk)
#pragma unroll
      for (int gp = 0; gp < 4; ++gp)
        acc[gp] = __builtin_amdgcn_mfma_f32_16x16x32_bf16(af[kk], bfW[gp][kk],
                                                          acc[gp], 0, 0, 0);
#pragma unroll
    for (int r = 0; r < 4; ++r) {
      const float iv = sigm(acc[0][r]);
      const float fv = sigm(acc[1][r]);
      const float gv = tanh_(acc[2][r]);
      const float ov = sigm(acc[3][r]);
      const float cc = fv * creg[r] + iv * gv;
      creg[r] = cc;
      hv[r] = ov * tanh_(cc);
    }
    // publish h(t+1) into slot (t+1)&3
    u16* hd = h_ring + (size_t)((t + 1) & 3) * 32768 + g * 4096;
#pragma unroll
    for (int r = 0; r < 4; ++r)
      hd[(lq * 4 + r) * 256 + colBase] = f2bf(hv[r]);
    if (l == 0)
      __hip_atomic_fetch_add(myflags + t + 1, 1u, __ATOMIC_RELEASE,
                             __HIP_MEMORY_SCOPE_AGENT);  // drains stores + wbl2 first
    // y(t) store (off critical path)
#pragma unroll
    for (int r = 0; r < 4; ++r)
      __builtin_nontemporal_store(
          hv[r], out + ((size_t)(g * 16 + lq * 4 + r) * 1024 + t) * 256 + colBase);
    // xg(t+1) = bias + x(t+1) @ Wi slice — in the peers' publish/poll shadow
    if (t < 1023) {
#pragma unroll
      for (int gp = 0; gp < 4; ++gp)
        xga[gp] = (floatx4){bias[gp], bias[gp], bias[gp], bias[gp]};
#pragma unroll
      for (int kk = 0; kk < 8; ++kk) {
        union { uint32_t u[4]; short8 s; } cv;
        cv.u[0] = packbf(xf[2 * kk][1], xf[2 * kk][0]);
        cv.u[1] = packbf(xf[2 * kk][3], xf[2 * kk][2]);
        cv.u[2] = packbf(xf[2 * kk + 1][1], xf[2 * kk + 1][0]);
        cv.u[3] = packbf(xf[2 * kk + 1][3], xf[2 * kk + 1][2]);
#pragma unroll
        for (int gp = 0; gp < 4; ++gp)
          xga[gp] = __builtin_amdgcn_mfma_f32_16x16x32_bf16(cv.s, bfI[gp][kk],
                                                            xga[gp], 0, 0, 0);
      }
    }
  }
  // finals: c_fin then h_fin after y
#pragma unroll
  for (int r = 0; r < 4; ++r) {
    const int b = g * 16 + lq * 4 + r;
    out[33554432 + b * 256 + colBase] = creg[r];
    out[33554432 + 32768 + b * 256 + colBase] = hv[r];
  }
}

// ---------- launch ----------
extern "C" void kernel_launch(void* const* d_in, const int* in_sizes, int n_in,
                              void* d_out, int out_size, void* d_ws, size_t ws_size,
                              hipStream_t stream) {
  const float* x  = (const float*)d_in[0];
  const float* Wi = (const float*)d_in[1];
  const float* Wh = (const float*)d_in[2];
  const float* bh = (const float*)d_in[3];
  char* ws = (char*)d_ws;
  // ws layout (1.5 MB total):
  //   [0,       512K)  Wi_t bf16 [1024][256]
  //   [512K,    1M)    Wh_t bf16 [1024][256]
  //   [1M,      +33K)  flags u32 [8][1025]
  //   [1.25M,   +256K) h ring bf16 [4][8][16][256]
  u16* Wi_t           = (u16*)(ws);
  u16* Wh_t           = (u16*)(ws + 524288);
  unsigned int* flags = (unsigned int*)(ws + 1048576);
  u16* h_ring         = (u16*)(ws + 1310720);
  float* out = (float*)d_out;

  hipMemsetAsync(flags, 0, 8 * 1025 * 4, stream);
  hipMemsetAsync(h_ring, 0, 4 * 65536, stream);   // h(0)=0 (slot 0; all 4 for hygiene)
  k1_prep<<<dim3(1024), dim3(256), 0, stream>>>(Wi, Wh, Wi_t, Wh_t);
  k3_lstm<<<dim3(128), dim3(64), 0, stream>>>(Wi_t, Wh_t, x, bh, h_ring, flags, out);
}